// Round 1
// baseline (138.677 us; speedup 1.0000x reference)
//
#include <hip/hip_runtime.h>

#define BDIM   256
#define GCHUNK 64      // gaussians per shade block (N=512 / 8 chunks)
#define NBINS  256     // 16x16 tiles of 32x32 px
#define SHF    28      // 27 SH coeffs (m*3+c) + invSy in slot 27 => 7 float4

// ---------------------------------------------------------------------------
// Pipeline: rays are counting-sorted into 32x32px tiles so each wave's 64
// rays are spatially local. Wave-vote skip rate on the heavy SH/exp body
// rises from ~85% (random ray order) to ~98.5%, and surviving votes have
// many active lanes instead of ~1. Per-gaussian derived params (tanh/sincos/
// exp/div) are computed once in pre_kernel instead of per-block.
// ---------------------------------------------------------------------------

__global__ void pre_kernel(const float* __restrict__ rgbsh,
                           const float* __restrict__ opacity,
                           const float* __restrict__ mu,
                           const float* __restrict__ scale,
                           const float* __restrict__ angle,
                           float4* __restrict__ wsA,   // ax, ay, bx, by
                           float4* __restrict__ wsB,   // cos, sin, sig(op), invSx
                           float*  __restrict__ wsSh,  // [N][28], slot 27 = invSy
                           int N)
{
    int n = blockIdx.x * blockDim.x + threadIdx.x;
    if (n >= N) return;
    const float S_MIN = 1.0f / 30.0f;
    const float S_MAX = 1.0f / 0.75f;
    float gmx = tanhf(mu[2 * n + 0]) * 1.05f;
    float gmy = tanhf(mu[2 * n + 1]) * 1.05f;
    float Sx = fminf(fmaxf(scale[2 * n + 0], 0.0f), 1.0f) * (S_MAX - S_MIN) + S_MIN;
    float Sy = fminf(fmaxf(scale[2 * n + 1], 0.0f), 1.0f) * (S_MAX - S_MIN) + S_MIN;
    float ax = 256.0f * Sx, ay = 256.0f * Sy;   // svec = pn*a + b
    wsA[n] = make_float4(ax, ay, -gmx * ax, -gmy * ay);
    float a = tanhf(angle[n]) * 3.1416f;
    float sa, ca;
    sincosf(a, &sa, &ca);
    float w0 = 1.0f / (1.0f + expf(-opacity[n]));
    wsB[n] = make_float4(ca, sa, w0, 1.0f / Sx);
    float* dst = wsSh + (size_t)n * SHF;
    #pragma unroll
    for (int m = 0; m < 27; ++m) dst[m] = rgbsh[n * 27 + m];
    dst[27] = 1.0f / Sy;
}

__device__ __forceinline__ int ray_tile(float px, float py) {
    int tx = ((int)px) >> 5;
    int ty = ((int)py) >> 5;
    tx = min(max(tx, 0), 15);
    ty = min(max(ty, 0), 15);
    return ty * 16 + tx;
}

__global__ void count_kernel(const float* __restrict__ x,
                             int* __restrict__ cnt, int* __restrict__ rank, int B)
{
    int b = blockIdx.x * blockDim.x + threadIdx.x;
    if (b >= B) return;
    float2 p = *(const float2*)(x + 2 * b);
    rank[b] = atomicAdd(&cnt[ray_tile(p.x, p.y)], 1);
}

__global__ void scan_kernel(const int* __restrict__ cnt, int* __restrict__ base)
{
    __shared__ int tmp[NBINS];
    int tid = threadIdx.x;
    int v = cnt[tid];
    tmp[tid] = v;
    __syncthreads();
    for (int off = 1; off < NBINS; off <<= 1) {
        int t = (tid >= off) ? tmp[tid - off] : 0;
        __syncthreads();
        tmp[tid] += t;
        __syncthreads();
    }
    base[tid] = tmp[tid] - v;   // exclusive scan
}

__global__ void scatter_kernel(const float* __restrict__ x,
                               const int* __restrict__ base,
                               const int* __restrict__ rank,
                               int* __restrict__ perm, int B)
{
    int b = blockIdx.x * blockDim.x + threadIdx.x;
    if (b >= B) return;
    float2 p = *(const float2*)(x + 2 * b);
    perm[base[ray_tile(p.x, p.y)] + rank[b]] = b;
}

__global__ __launch_bounds__(BDIM, 4) void shade_kernel(
    const float*  __restrict__ x,      // (B,2)
    const int*    __restrict__ perm,   // (B) sorted->orig ray index
    const float4* __restrict__ wsA,
    const float4* __restrict__ wsB,
    const float4* __restrict__ wsSh4,  // [N][7]
    float* __restrict__ out,           // (B,3)
    int B, int N)
{
    __shared__ float4 gA[GCHUNK];
    __shared__ float4 gB[GCHUNK];
    __shared__ float4 gS[GCHUNK][7];   // SH coeffs + invSy in [6].w

    const int g0  = blockIdx.y * GCHUNK;
    const int tid = threadIdx.x;

    if (tid < GCHUNK) {
        gA[tid] = wsA[g0 + tid];
        gB[tid] = wsB[g0 + tid];
    }
    for (int i = tid; i < GCHUNK * 7; i += BDIM)
        (&gS[0][0])[i] = wsSh4[(size_t)g0 * 7 + i];
    __syncthreads();

    const int b   = blockIdx.x * BDIM + tid;
    const int bb  = (b < B) ? b : (B - 1);
    const int ray = perm[bb];
    float2 px = *(const float2*)(x + 2 * ray);
    float pnx = px.x * (1.0f / 256.0f) - 1.0f;
    float pny = px.y * (1.0f / 256.0f) - 1.0f;

    float accR = 0.0f, accG = 0.0f, accB = 0.0f;

    #pragma unroll 4
    for (int j = 0; j < GCHUNK; ++j) {
        float4 p = gA[j];
        float sx = fmaf(pnx, p.x, p.z);            // scaled offset
        float sy = fmaf(pny, p.y, p.w);
        float t  = fmaf(sx, sx, sy * sy);          // == dist^2 (R is rotation)
        bool  v  = t < 25.0f;
        if (__any(v)) {
            if (v) {
                float4 q  = gB[j];
                float4 h6 = gS[j][6];
                float c = q.x, s = q.y;
                float rx = fmaf(c, sx, -s * sy);
                float ry = fmaf(s, sx,  c * sy);
                float d2 = fmaf(rx, rx, ry * ry);
                float vx  = sx * q.w;              // pixel-space vec
                float vy  = sy * h6.w;
                float len = sqrtf(fmaf(vx, vx, vy * vy));
                float inv = __builtin_amdgcn_rcpf(1e-10f + len);
                float rvx = fmaf(c, vx, -s * vy);
                float rvy = fmaf(s, vx,  c * vy);
                float s1 = rvx * inv, c1 = rvy * inv;
                float s2 = 2.0f * s1 * c1;
                float c2 = fmaf(c1, c1, -s1 * s1);
                float s3 = fmaf(s2, c1,  c2 * s1);
                float c3 = fmaf(c2, c1, -s2 * s1);
                float s4 = 2.0f * s2 * c2;
                float c4 = fmaf(c2, c2, -s2 * s2);
                float4 h0 = gS[j][0], h1 = gS[j][1], h2 = gS[j][2];
                float4 h3 = gS[j][3], h4 = gS[j][4], h5 = gS[j][5];
                float r  = h0.x, g = h0.y, bl = h0.z;
                r = fmaf(s1, h0.w, r);  g = fmaf(s1, h1.x, g);  bl = fmaf(s1, h1.y, bl);
                r = fmaf(c1, h1.z, r);  g = fmaf(c1, h1.w, g);  bl = fmaf(c1, h2.x, bl);
                r = fmaf(s2, h2.y, r);  g = fmaf(s2, h2.z, g);  bl = fmaf(s2, h2.w, bl);
                r = fmaf(c2, h3.x, r);  g = fmaf(c2, h3.y, g);  bl = fmaf(c2, h3.z, bl);
                r = fmaf(s3, h3.w, r);  g = fmaf(s3, h4.x, g);  bl = fmaf(s3, h4.y, bl);
                r = fmaf(c3, h4.z, r);  g = fmaf(c3, h4.w, g);  bl = fmaf(c3, h5.x, bl);
                r = fmaf(s4, h5.y, r);  g = fmaf(s4, h5.z, g);  bl = fmaf(s4, h5.w, bl);
                r = fmaf(c4, h6.x, r);  g = fmaf(c4, h6.y, g);  bl = fmaf(c4, h6.z, bl);
                r  = __builtin_amdgcn_rcpf(1.0f + __expf(-r));
                g  = __builtin_amdgcn_rcpf(1.0f + __expf(-g));
                bl = __builtin_amdgcn_rcpf(1.0f + __expf(-bl));
                float w = __expf(-d2) * q.z;
                accR = fmaf(w, r,  accR);
                accG = fmaf(w, g,  accG);
                accB = fmaf(w, bl, accB);
            }
        }
    }

    if (b < B) {
        atomicAdd(&out[3 * ray + 0], accR);
        atomicAdd(&out[3 * ray + 1], accG);
        atomicAdd(&out[3 * ray + 2], accB);
    }
}

extern "C" void kernel_launch(void* const* d_in, const int* in_sizes, int n_in,
                              void* d_out, int out_size, void* d_ws, size_t ws_size,
                              hipStream_t stream) {
    const float* x       = (const float*)d_in[0];
    const float* rgbsh   = (const float*)d_in[1];
    const float* opacity = (const float*)d_in[2];
    const float* mu      = (const float*)d_in[3];
    const float* scale   = (const float*)d_in[4];
    const float* angle   = (const float*)d_in[5];
    float* out = (float*)d_out;

    const int B = in_sizes[0] / 2;   // 32768
    const int N = in_sizes[2];       // 512

    // workspace layout (all 16B-aligned where needed)
    char* ws = (char*)d_ws;
    size_t offA    = 0;                              // float4[N]
    size_t offB    = offA    + (size_t)N * 16;       // float4[N]
    size_t offSh   = offB    + (size_t)N * 16;       // float[N][28] == float4[N][7]
    size_t offCnt  = offSh   + (size_t)N * SHF * 4;  // int[NBINS]
    size_t offBase = offCnt  + NBINS * 4;            // int[NBINS]
    size_t offRank = offBase + NBINS * 4;            // int[B]
    size_t offPerm = offRank + (size_t)B * 4;        // int[B]

    float4* wsA   = (float4*)(ws + offA);
    float4* wsB   = (float4*)(ws + offB);
    float*  wsSh  = (float*)(ws + offSh);
    int*    cnt   = (int*)(ws + offCnt);
    int*    base  = (int*)(ws + offBase);
    int*    rank  = (int*)(ws + offRank);
    int*    perm  = (int*)(ws + offPerm);

    // zero atomic-accumulated output + tile counters (graph-safe)
    hipMemsetAsync(out, 0, (size_t)out_size * sizeof(float), stream);
    hipMemsetAsync(cnt, 0, NBINS * sizeof(int), stream);

    pre_kernel<<<(N + 255) / 256, 256, 0, stream>>>(rgbsh, opacity, mu, scale,
                                                    angle, wsA, wsB, wsSh, N);
    count_kernel<<<(B + 255) / 256, 256, 0, stream>>>(x, cnt, rank, B);
    scan_kernel<<<1, NBINS, 0, stream>>>(cnt, base);
    scatter_kernel<<<(B + 255) / 256, 256, 0, stream>>>(x, base, rank, perm, B);

    dim3 grid((B + BDIM - 1) / BDIM, N / GCHUNK);
    shade_kernel<<<grid, BDIM, 0, stream>>>(x, perm, wsA, wsB,
                                            (const float4*)wsSh, out, B, N);
}

// Round 2
// 121.392 us; speedup vs baseline: 1.1424x; 1.1424x over previous
//
#include <hip/hip_runtime.h>

#define NB    256      // blocks == tiles (16x16 grid of 32x32px tiles)
#define BDIM  256
#define NT    256
#define LCAP  128      // gaussians staged in LDS per chunk
#define CSTR  16       // global bin padding stride in ints (64B -> no line sharing)

// ---------------------------------------------------------------------------
// One-kernel gsplat-style pipeline. 256 blocks (<= CU count; ~23KB LDS =>
// capacity far exceeds grid, all blocks co-resident) synchronized by a
// monotonic device-scope atomic barrier. Phases:
//   A: per-block LDS histogram of its 128 rays -> padded global bins
//   B: every block replicates the 256-bin exclusive scan, scatters perm
//   C: wave-0 ballot-compacts the gaussians overlapping this block's tile
//      (conservative axis-aligned 5-sigma AABB vs tile AABB)
//   D: stage listed-gaussian params in LDS, each thread fully shades one ray
//      (ascending-n order == reference order), plain stores, no atomics.
// ---------------------------------------------------------------------------

__device__ __forceinline__ void grid_barrier(int* bar, int target) {
    __syncthreads();
    if (threadIdx.x == 0) {
        __threadfence();
        __hip_atomic_fetch_add(bar, 1, __ATOMIC_RELAXED, __HIP_MEMORY_SCOPE_AGENT);
        while (__hip_atomic_load(bar, __ATOMIC_RELAXED, __HIP_MEMORY_SCOPE_AGENT) < target)
            __builtin_amdgcn_s_sleep(2);
        __threadfence();
    }
    __syncthreads();
}

__global__ __launch_bounds__(BDIM) void mega_kernel(
    const float* __restrict__ x,        // (B,2)
    const float* __restrict__ rgbsh,    // (N,9,3)
    const float* __restrict__ opacity,  // (N)
    const float* __restrict__ mu,       // (N,2)
    const float* __restrict__ scale,    // (N,2)
    const float* __restrict__ angle,    // (N)
    float* __restrict__ out,            // (B,3)
    int* __restrict__ cnt,              // [NT*CSTR], zeroed
    int* __restrict__ bar,              // [1], zeroed
    int* __restrict__ perm,             // [B]
    int B, int N)
{
    __shared__ int   hist[NT];          // phase A hist, reused as scan buffer
    __shared__ int   bbase[NT];
    __shared__ int   tot[NT];
    __shared__ int   sbase[NT];
    __shared__ unsigned short list[512];
    __shared__ int   lcnt_s;
    __shared__ float4 lA[LCAP];         // ax, ay, bx, by
    __shared__ float4 lB[LCAP];         // cos, sin, sig(op), 1/Sx
    __shared__ float4 lS[LCAP][7];      // 27 SH coeffs + 1/Sy in [6].w

    const int tid = threadIdx.x;
    const int blk = blockIdx.x;
    const float SMIN = 1.0f / 30.0f, SMAX = 1.0f / 0.75f;

    // ---------- phase A: count this block's rays into tiles ----------
    hist[tid] = 0;
    __syncthreads();
    const int rpb = (B + NB - 1) / NB;            // 128 (<= BDIM)
    const int myray = blk * rpb + tid;
    int mytile = -1, lrank = 0;
    if (tid < rpb && myray < B) {
        float2 p = *(const float2*)(x + 2 * myray);
        int tx = min(max(((int)p.x) >> 5, 0), 15);
        int ty = min(max(((int)p.y) >> 5, 0), 15);
        mytile = ty * 16 + tx;
        lrank = atomicAdd(&hist[mytile], 1);      // LDS atomic, returns local rank
    }
    __syncthreads();
    {
        int h = hist[tid];
        if (h > 0)
            bbase[tid] = __hip_atomic_fetch_add(&cnt[tid * CSTR], h,
                              __ATOMIC_RELAXED, __HIP_MEMORY_SCOPE_AGENT);
    }
    __syncthreads();
    const int grank = (mytile >= 0) ? (bbase[mytile] + lrank) : 0;

    grid_barrier(bar, NB);

    // ---------- phase B: replicated exclusive scan + scatter ----------
    int t0 = __hip_atomic_load(&cnt[tid * CSTR], __ATOMIC_RELAXED,
                               __HIP_MEMORY_SCOPE_AGENT);
    tot[tid]  = t0;
    hist[tid] = t0;
    __syncthreads();
    for (int off = 1; off < NT; off <<= 1) {
        int tv = (tid >= off) ? hist[tid - off] : 0;
        __syncthreads();
        hist[tid] += tv;
        __syncthreads();
    }
    sbase[tid] = hist[tid] - t0;                  // exclusive scan
    __syncthreads();
    if (mytile >= 0)
        __hip_atomic_store(&perm[sbase[mytile] + grank], myray,
                           __ATOMIC_RELAXED, __HIP_MEMORY_SCOPE_AGENT);

    grid_barrier(bar, 2 * NB);

    // ---------- phase C: cull gaussians for this tile (wave 0) ----------
    const float tcx = (float)((blk & 15) * 32 + 16);
    const float tcy = (float)((blk >> 4) * 32 + 16);
    if (tid < 64) {
        int basec = 0;
        const int chunks = (N + 63) >> 6;
        for (int k = 0; k < chunks; ++k) {
            int n = k * 64 + tid;
            bool pass = false;
            if (n < N) {
                float gcx = (tanhf(mu[2 * n + 0]) * 1.05f + 1.0f) * 256.0f;
                float gcy = (tanhf(mu[2 * n + 1]) * 1.05f + 1.0f) * 256.0f;
                float Sx = fminf(fmaxf(scale[2 * n + 0], 0.f), 1.f) * (SMAX - SMIN) + SMIN;
                float Sy = fminf(fmaxf(scale[2 * n + 1], 0.f), 1.f) * (SMAX - SMIN) + SMIN;
                // ray invalid for whole tile unless |c - tile_center| <= 16 + 5/S (+eps)
                pass = (fabsf(gcx - tcx) <= 16.5f + 5.0f / Sx) &&
                       (fabsf(gcy - tcy) <= 16.5f + 5.0f / Sy);
            }
            unsigned long long mb = __ballot(pass);
            int off = __popcll(mb & ((1ull << tid) - 1ull));
            if (pass) list[basec + off] = (unsigned short)n;  // ascending-n order
            basec += __popcll(mb);
        }
        if (tid == 0) lcnt_s = basec;
    }
    __syncthreads();
    const int lcnt = lcnt_s;

    // ---------- phase D: shade this tile's rays ----------
    const int rbase = sbase[blk];
    const int rcnt  = tot[blk];
    const int riter = (rcnt + BDIM - 1) / BDIM;   // uniform trip count
    for (int r = 0; r < riter; ++r) {
        const int ri = r * BDIM + tid;
        const bool act = (ri < rcnt);
        int ray = 0; float pnx = 0.f, pny = 0.f;
        if (act) {
            ray = __hip_atomic_load(&perm[rbase + ri], __ATOMIC_RELAXED,
                                    __HIP_MEMORY_SCOPE_AGENT);
            float2 p = *(const float2*)(x + 2 * ray);
            pnx = p.x * (1.0f / 256.0f) - 1.0f;
            pny = p.y * (1.0f / 256.0f) - 1.0f;
        }
        float accR = 0.f, accG = 0.f, accB = 0.f;
        for (int c0 = 0; c0 < lcnt; c0 += LCAP) {
            const int m = min(LCAP, lcnt - c0);
            __syncthreads();
            if (tid < m) {                        // stage params for this chunk
                int n = list[c0 + tid];
                float gmx = tanhf(mu[2 * n + 0]) * 1.05f;
                float gmy = tanhf(mu[2 * n + 1]) * 1.05f;
                float Sx = fminf(fmaxf(scale[2 * n + 0], 0.f), 1.f) * (SMAX - SMIN) + SMIN;
                float Sy = fminf(fmaxf(scale[2 * n + 1], 0.f), 1.f) * (SMAX - SMIN) + SMIN;
                float ax = 256.0f * Sx, ay = 256.0f * Sy;
                lA[tid] = make_float4(ax, ay, -gmx * ax, -gmy * ay);
                float a = tanhf(angle[n]) * 3.1416f;
                float sa, ca; sincosf(a, &sa, &ca);
                float w0 = 1.0f / (1.0f + expf(-opacity[n]));
                lB[tid] = make_float4(ca, sa, w0, 1.0f / Sx);
                const float* sh = rgbsh + n * 27;
                float buf[28];
                #pragma unroll
                for (int q = 0; q < 27; ++q) buf[q] = sh[q];
                buf[27] = 1.0f / Sy;
                #pragma unroll
                for (int q = 0; q < 7; ++q)
                    lS[tid][q] = make_float4(buf[4*q], buf[4*q+1], buf[4*q+2], buf[4*q+3]);
            }
            __syncthreads();
            if (act) {
                for (int j = 0; j < m; ++j) {
                    float4 pa = lA[j];
                    float sx = fmaf(pnx, pa.x, pa.z);
                    float sy = fmaf(pny, pa.y, pa.w);
                    float d  = fmaf(sx, sx, sy * sy);   // == dist^2
                    bool v = d < 25.0f;
                    if (__any(v)) {
                        if (v) {
                            float4 q  = lB[j];
                            float4 h6 = lS[j][6];
                            float c = q.x, s = q.y;
                            float rx = fmaf(c, sx, -s * sy);
                            float ry = fmaf(s, sx,  c * sy);
                            float d2 = fmaf(rx, rx, ry * ry);
                            float vx  = sx * q.w;
                            float vy  = sy * h6.w;
                            float len = sqrtf(fmaf(vx, vx, vy * vy));
                            float inv = __builtin_amdgcn_rcpf(1e-10f + len);
                            float rvx = fmaf(c, vx, -s * vy);
                            float rvy = fmaf(s, vx,  c * vy);
                            float s1 = rvx * inv, c1 = rvy * inv;
                            float s2 = 2.0f * s1 * c1;
                            float c2 = fmaf(c1, c1, -s1 * s1);
                            float s3 = fmaf(s2, c1,  c2 * s1);
                            float c3 = fmaf(c2, c1, -s2 * s1);
                            float s4 = 2.0f * s2 * c2;
                            float c4 = fmaf(c2, c2, -s2 * s2);
                            float4 h0 = lS[j][0], h1 = lS[j][1], h2 = lS[j][2];
                            float4 h3 = lS[j][3], h4 = lS[j][4], h5 = lS[j][5];
                            float rr = h0.x, gg = h0.y, bb = h0.z;
                            rr = fmaf(s1, h0.w, rr);  gg = fmaf(s1, h1.x, gg);  bb = fmaf(s1, h1.y, bb);
                            rr = fmaf(c1, h1.z, rr);  gg = fmaf(c1, h1.w, gg);  bb = fmaf(c1, h2.x, bb);
                            rr = fmaf(s2, h2.y, rr);  gg = fmaf(s2, h2.z, gg);  bb = fmaf(s2, h2.w, bb);
                            rr = fmaf(c2, h3.x, rr);  gg = fmaf(c2, h3.y, gg);  bb = fmaf(c2, h3.z, bb);
                            rr = fmaf(s3, h3.w, rr);  gg = fmaf(s3, h4.x, gg);  bb = fmaf(s3, h4.y, bb);
                            rr = fmaf(c3, h4.z, rr);  gg = fmaf(c3, h4.w, gg);  bb = fmaf(c3, h5.x, bb);
                            rr = fmaf(s4, h5.y, rr);  gg = fmaf(s4, h5.z, gg);  bb = fmaf(s4, h5.w, bb);
                            rr = fmaf(c4, h6.x, rr);  gg = fmaf(c4, h6.y, gg);  bb = fmaf(c4, h6.z, bb);
                            rr = __builtin_amdgcn_rcpf(1.0f + __expf(-rr));
                            gg = __builtin_amdgcn_rcpf(1.0f + __expf(-gg));
                            bb = __builtin_amdgcn_rcpf(1.0f + __expf(-bb));
                            float w = __expf(-d2) * q.z;
                            accR = fmaf(w, rr, accR);
                            accG = fmaf(w, gg, accG);
                            accB = fmaf(w, bb, accB);
                        }
                    }
                }
            }
        }
        if (act) {
            out[3 * ray + 0] = accR;
            out[3 * ray + 1] = accG;
            out[3 * ray + 2] = accB;
        }
    }
}

extern "C" void kernel_launch(void* const* d_in, const int* in_sizes, int n_in,
                              void* d_out, int out_size, void* d_ws, size_t ws_size,
                              hipStream_t stream) {
    const float* x       = (const float*)d_in[0];
    const float* rgbsh   = (const float*)d_in[1];
    const float* opacity = (const float*)d_in[2];
    const float* mu      = (const float*)d_in[3];
    const float* scale   = (const float*)d_in[4];
    const float* angle   = (const float*)d_in[5];
    float* out = (float*)d_out;

    const int B = in_sizes[0] / 2;   // 32768
    const int N = in_sizes[2];       // 512

    // workspace: [cnt: NT*CSTR ints = 16KB][bar: 16 ints][perm: B ints]
    char* ws = (char*)d_ws;
    int* cnt  = (int*)(ws);
    int* bar  = (int*)(ws + (size_t)NT * CSTR * 4);
    int* perm = (int*)(ws + (size_t)NT * CSTR * 4 + 64);

    // zero bins + barrier counter (out needs no memset: plain stores cover all rays)
    hipMemsetAsync(cnt, 0, (size_t)NT * CSTR * 4 + 64, stream);

    mega_kernel<<<NB, BDIM, 0, stream>>>(x, rgbsh, opacity, mu, scale, angle,
                                         out, cnt, bar, perm, B, N);
}

// Round 3
// 82.244 us; speedup vs baseline: 1.6862x; 1.4760x over previous
//
#include <hip/hip_runtime.h>

#define BDIM 512       // 8 waves: each wave owns a 64-gaussian chunk
#define RPB  64        // rays per block (one per lane)
#define NW   8         // waves per block
#define NG   512       // gaussians (N)

// ---------------------------------------------------------------------------
// No sort, no atomics, no grid barriers, no output memset.
// pre_kernel: per-gaussian derived params -> ws (float4-packed).
// splat_kernel: block = 64 rays x all 512 gaussians. Wave w handles chunk
// [64w, 64w+64): all 64 lanes walk the same gaussian (LDS broadcast) with a
// wave-vote skipping the heavy SH/exp body. Partials reduce across waves in
// LDS (ascending chunk order == ascending n), one coalesced store per ray.
// LDS = 79,872 B < 80 KB  =>  2 blocks/CU = 16 waves/CU (4/SIMD).
// ---------------------------------------------------------------------------

__global__ void pre_kernel(const float* __restrict__ rgbsh,
                           const float* __restrict__ opacity,
                           const float* __restrict__ mu,
                           const float* __restrict__ scale,
                           const float* __restrict__ angle,
                           float4* __restrict__ wsA,   // ax, ay, bx, by
                           float4* __restrict__ wsB,   // cos, sin, sig(op), 1/Sx
                           float4* __restrict__ wsSh,  // [N][7]: 27 SH + 1/Sy
                           int N)
{
    int n = blockIdx.x * blockDim.x + threadIdx.x;
    if (n >= N) return;
    const float S_MIN = 1.0f / 30.0f;
    const float S_MAX = 1.0f / 0.75f;
    float gmx = tanhf(mu[2 * n + 0]) * 1.05f;
    float gmy = tanhf(mu[2 * n + 1]) * 1.05f;
    float Sx = fminf(fmaxf(scale[2 * n + 0], 0.0f), 1.0f) * (S_MAX - S_MIN) + S_MIN;
    float Sy = fminf(fmaxf(scale[2 * n + 1], 0.0f), 1.0f) * (S_MAX - S_MIN) + S_MIN;
    float ax = 256.0f * Sx, ay = 256.0f * Sy;      // svec = pn*a + b
    wsA[n] = make_float4(ax, ay, -gmx * ax, -gmy * ay);
    float a = tanhf(angle[n]) * 3.1416f;
    float sa, ca;
    sincosf(a, &sa, &ca);
    float w0 = 1.0f / (1.0f + expf(-opacity[n]));
    wsB[n] = make_float4(ca, sa, w0, 1.0f / Sx);
    const float* sh = rgbsh + n * 27;
    float buf[28];
    #pragma unroll
    for (int q = 0; q < 27; ++q) buf[q] = sh[q];
    buf[27] = 1.0f / Sy;
    #pragma unroll
    for (int q = 0; q < 7; ++q)
        wsSh[n * 7 + q] = make_float4(buf[4*q], buf[4*q+1], buf[4*q+2], buf[4*q+3]);
}

__global__ __launch_bounds__(BDIM, 4) void splat_kernel(
    const float*  __restrict__ x,      // (B,2)
    const float4* __restrict__ wsA,
    const float4* __restrict__ wsB,
    const float4* __restrict__ wsSh,   // [N][7]
    float* __restrict__ out,           // (B,3)
    int B)
{
    __shared__ float4 gA[NG];          //  8 KB
    __shared__ float4 gB[NG];          //  8 KB
    __shared__ float4 gS[NG * 7];      // 56 KB ([n][7] layout)
    __shared__ float  acc[NW * RPB * 3]; // 6 KB
    const int tid = threadIdx.x;

    // ---- stage all gaussian params (coalesced float4) ----
    if (tid < NG) { gA[tid] = wsA[tid]; gB[tid] = wsB[tid]; }
    #pragma unroll
    for (int i = tid; i < NG * 7; i += BDIM) gS[i] = wsSh[i];
    __syncthreads();

    // ---- per-ray setup ----
    const int lane = tid & 63;
    const int w    = tid >> 6;                     // wave id = gaussian chunk
    const int b    = blockIdx.x * RPB + lane;
    const int bb   = (b < B) ? b : (B - 1);
    float2 p2 = *(const float2*)(x + 2 * bb);
    float pnx = p2.x * (1.0f / 256.0f) - 1.0f;
    float pny = p2.y * (1.0f / 256.0f) - 1.0f;

    float accR = 0.0f, accG = 0.0f, accB = 0.0f;
    const int g0 = w * 64;

    for (int j = 0; j < 64; ++j) {
        const int g = g0 + j;
        float4 pa = gA[g];
        float sx = fmaf(pnx, pa.x, pa.z);          // scaled offset
        float sy = fmaf(pny, pa.y, pa.w);
        float t  = fmaf(sx, sx, sy * sy);          // == dist^2 (R is rotation)
        bool  v  = t < 25.0f;
        if (__any(v)) {
            if (v) {
                float4 q  = gB[g];
                float4 h6 = gS[g * 7 + 6];
                float c = q.x, s = q.y;
                float rx = fmaf(c, sx, -s * sy);
                float ry = fmaf(s, sx,  c * sy);
                float d2 = fmaf(rx, rx, ry * ry);
                float vx  = sx * q.w;              // pixel-space vec
                float vy  = sy * h6.w;
                float len = sqrtf(fmaf(vx, vx, vy * vy));
                float inv = __builtin_amdgcn_rcpf(1e-10f + len);
                float rvx = fmaf(c, vx, -s * vy);
                float rvy = fmaf(s, vx,  c * vy);
                float s1 = rvx * inv, c1 = rvy * inv;
                float s2 = 2.0f * s1 * c1;
                float c2 = fmaf(c1, c1, -s1 * s1);
                float s3 = fmaf(s2, c1,  c2 * s1);
                float c3 = fmaf(c2, c1, -s2 * s1);
                float s4 = 2.0f * s2 * c2;
                float c4 = fmaf(c2, c2, -s2 * s2);
                float4 h0 = gS[g*7+0], h1 = gS[g*7+1], h2 = gS[g*7+2];
                float4 h3 = gS[g*7+3], h4 = gS[g*7+4], h5 = gS[g*7+5];
                float rr = h0.x, gg = h0.y, bb2 = h0.z;
                rr = fmaf(s1, h0.w, rr);  gg = fmaf(s1, h1.x, gg);  bb2 = fmaf(s1, h1.y, bb2);
                rr = fmaf(c1, h1.z, rr);  gg = fmaf(c1, h1.w, gg);  bb2 = fmaf(c1, h2.x, bb2);
                rr = fmaf(s2, h2.y, rr);  gg = fmaf(s2, h2.z, gg);  bb2 = fmaf(s2, h2.w, bb2);
                rr = fmaf(c2, h3.x, rr);  gg = fmaf(c2, h3.y, gg);  bb2 = fmaf(c2, h3.z, bb2);
                rr = fmaf(s3, h3.w, rr);  gg = fmaf(s3, h4.x, gg);  bb2 = fmaf(s3, h4.y, bb2);
                rr = fmaf(c3, h4.z, rr);  gg = fmaf(c3, h4.w, gg);  bb2 = fmaf(c3, h5.x, bb2);
                rr = fmaf(s4, h5.y, rr);  gg = fmaf(s4, h5.z, gg);  bb2 = fmaf(s4, h5.w, bb2);
                rr = fmaf(c4, h6.x, rr);  gg = fmaf(c4, h6.y, gg);  bb2 = fmaf(c4, h6.z, bb2);
                rr  = __builtin_amdgcn_rcpf(1.0f + __expf(-rr));
                gg  = __builtin_amdgcn_rcpf(1.0f + __expf(-gg));
                bb2 = __builtin_amdgcn_rcpf(1.0f + __expf(-bb2));
                float wt = __expf(-d2) * q.z;
                accR = fmaf(wt, rr,  accR);
                accG = fmaf(wt, gg,  accG);
                accB = fmaf(wt, bb2, accB);
            }
        }
    }

    // ---- reduce partials across the 8 waves (ascending chunk == ascending n) ----
    acc[(w * RPB + lane) * 3 + 0] = accR;
    acc[(w * RPB + lane) * 3 + 1] = accG;
    acc[(w * RPB + lane) * 3 + 2] = accB;
    __syncthreads();
    if (tid < RPB * 3) {
        float s = 0.0f;
        #pragma unroll
        for (int w2 = 0; w2 < NW; ++w2)
            s += acc[w2 * RPB * 3 + tid];          // contiguous: addr = 4*tid
        const int ray = blockIdx.x * RPB + tid / 3;
        if (ray < B)
            out[(size_t)blockIdx.x * RPB * 3 + tid] = s;
    }
}

extern "C" void kernel_launch(void* const* d_in, const int* in_sizes, int n_in,
                              void* d_out, int out_size, void* d_ws, size_t ws_size,
                              hipStream_t stream) {
    const float* x       = (const float*)d_in[0];
    const float* rgbsh   = (const float*)d_in[1];
    const float* opacity = (const float*)d_in[2];
    const float* mu      = (const float*)d_in[3];
    const float* scale   = (const float*)d_in[4];
    const float* angle   = (const float*)d_in[5];
    float* out = (float*)d_out;

    const int B = in_sizes[0] / 2;   // 32768
    const int N = in_sizes[2];       // 512

    // workspace: [wsA: N float4][wsB: N float4][wsSh: N*7 float4]
    char* ws = (char*)d_ws;
    float4* wsA  = (float4*)(ws);
    float4* wsB  = (float4*)(ws + (size_t)N * 16);
    float4* wsSh = (float4*)(ws + (size_t)N * 32);

    pre_kernel<<<(N + 255) / 256, 256, 0, stream>>>(rgbsh, opacity, mu, scale,
                                                    angle, wsA, wsB, wsSh, N);
    splat_kernel<<<(B + RPB - 1) / RPB, BDIM, 0, stream>>>(x, wsA, wsB, wsSh,
                                                           out, B);
}

// Round 4
// 77.157 us; speedup vs baseline: 1.7973x; 1.0659x over previous
//
#include <hip/hip_runtime.h>

#define BDIM 1024      // 16 waves: each wave owns a 32-gaussian chunk
#define NW   16
#define RPB  64        // rays per block (one per lane)
#define NG   512       // gaussians (N)
#define GPW  (NG / NW) // 32 gaussians per wave

// ---------------------------------------------------------------------------
// No sort, no atomics, no grid barriers, no output memset.
// pre_kernel: per-gaussian derived params -> ws (float4-packed).
// splat_kernel: block = 64 rays x all 512 gaussians; wave w walks chunk
// [32w, 32w+32) with all 64 lanes on the same gaussian (LDS broadcast for the
// cheap test, wave-vote gating the heavy SH/exp body). SH coeffs are NOT
// staged in LDS (only ~15% of iters touch them) -- read from L2-resident ws
// via wave-uniform scalarized loads. LDS = 28.7 KB => 2 blocks/CU = 32
// waves/CU (8/SIMD, full occupancy). Partials reduce across waves in LDS
// (ascending chunk order == ascending n), one coalesced store per ray.
// ---------------------------------------------------------------------------

__global__ void pre_kernel(const float* __restrict__ rgbsh,
                           const float* __restrict__ opacity,
                           const float* __restrict__ mu,
                           const float* __restrict__ scale,
                           const float* __restrict__ angle,
                           float4* __restrict__ wsA,   // ax, ay, bx, by
                           float4* __restrict__ wsB,   // cos, sin, sig(op), 1/Sx
                           float4* __restrict__ wsSh,  // [N][7]: 27 SH + 1/Sy
                           int N)
{
    int n = blockIdx.x * blockDim.x + threadIdx.x;
    if (n >= N) return;
    const float S_MIN = 1.0f / 30.0f;
    const float S_MAX = 1.0f / 0.75f;
    float gmx = tanhf(mu[2 * n + 0]) * 1.05f;
    float gmy = tanhf(mu[2 * n + 1]) * 1.05f;
    float Sx = fminf(fmaxf(scale[2 * n + 0], 0.0f), 1.0f) * (S_MAX - S_MIN) + S_MIN;
    float Sy = fminf(fmaxf(scale[2 * n + 1], 0.0f), 1.0f) * (S_MAX - S_MIN) + S_MIN;
    float ax = 256.0f * Sx, ay = 256.0f * Sy;      // svec = pn*a + b
    wsA[n] = make_float4(ax, ay, -gmx * ax, -gmy * ay);
    float a = tanhf(angle[n]) * 3.1416f;
    float sa, ca;
    sincosf(a, &sa, &ca);
    float w0 = 1.0f / (1.0f + expf(-opacity[n]));
    wsB[n] = make_float4(ca, sa, w0, 1.0f / Sx);
    const float* sh = rgbsh + n * 27;
    float buf[28];
    #pragma unroll
    for (int q = 0; q < 27; ++q) buf[q] = sh[q];
    buf[27] = 1.0f / Sy;
    #pragma unroll
    for (int q = 0; q < 7; ++q)
        wsSh[n * 7 + q] = make_float4(buf[4*q], buf[4*q+1], buf[4*q+2], buf[4*q+3]);
}

__global__ __launch_bounds__(BDIM, 8) void splat_kernel(
    const float*  __restrict__ x,      // (B,2)
    const float4* __restrict__ wsA,
    const float4* __restrict__ wsB,
    const float4* __restrict__ wsSh,   // [N][7], read directly (L2-resident)
    float* __restrict__ out,           // (B,3)
    int B)
{
    __shared__ float4 gA[NG];               // 8 KB
    __shared__ float4 gB[NG];               // 8 KB
    __shared__ float  acc[NW][RPB * 3];     // 12 KB
    const int tid = threadIdx.x;

    // ---- stage cheap-path params (coalesced float4) ----
    if (tid < NG)          gA[tid]      = wsA[tid];
    else                   gB[tid - NG] = wsB[tid - NG];
    __syncthreads();

    // ---- per-ray setup ----
    const int lane = tid & 63;
    const int w    = tid >> 6;                     // wave id = gaussian chunk
    const int b    = blockIdx.x * RPB + lane;
    const int bb   = (b < B) ? b : (B - 1);
    float2 p2 = *(const float2*)(x + 2 * bb);
    float pnx = p2.x * (1.0f / 256.0f) - 1.0f;
    float pny = p2.y * (1.0f / 256.0f) - 1.0f;

    float accR = 0.0f, accG = 0.0f, accB = 0.0f;
    const int g0 = w * GPW;

    #pragma unroll 4
    for (int j = 0; j < GPW; ++j) {
        const int g = g0 + j;
        float4 pa = gA[g];
        float sx = fmaf(pnx, pa.x, pa.z);          // scaled offset
        float sy = fmaf(pny, pa.y, pa.w);
        float t  = fmaf(sx, sx, sy * sy);          // == dist^2 (R is rotation)
        bool  v  = t < 25.0f;
        if (__any(v)) {
            if (v) {
                float4 q = gB[g];
                // wave-uniform SH address -> scalarized broadcast loads
                const int gu = __builtin_amdgcn_readfirstlane(g);
                const float4* sh = wsSh + gu * 7;
                float4 h6 = sh[6];
                float c = q.x, s = q.y;
                float rx = fmaf(c, sx, -s * sy);
                float ry = fmaf(s, sx,  c * sy);
                float d2 = fmaf(rx, rx, ry * ry);
                float vx  = sx * q.w;              // pixel-space vec
                float vy  = sy * h6.w;
                float len = sqrtf(fmaf(vx, vx, vy * vy));
                float inv = __builtin_amdgcn_rcpf(1e-10f + len);
                float rvx = fmaf(c, vx, -s * vy);
                float rvy = fmaf(s, vx,  c * vy);
                float s1 = rvx * inv, c1 = rvy * inv;
                float s2 = 2.0f * s1 * c1;
                float c2 = fmaf(c1, c1, -s1 * s1);
                float s3 = fmaf(s2, c1,  c2 * s1);
                float c3 = fmaf(c2, c1, -s2 * s1);
                float s4 = 2.0f * s2 * c2;
                float c4 = fmaf(c2, c2, -s2 * s2);
                float4 h0 = sh[0], h1 = sh[1], h2 = sh[2];
                float4 h3 = sh[3], h4 = sh[4], h5 = sh[5];
                float rr = h0.x, gg = h0.y, bb2 = h0.z;
                rr = fmaf(s1, h0.w, rr);  gg = fmaf(s1, h1.x, gg);  bb2 = fmaf(s1, h1.y, bb2);
                rr = fmaf(c1, h1.z, rr);  gg = fmaf(c1, h1.w, gg);  bb2 = fmaf(c1, h2.x, bb2);
                rr = fmaf(s2, h2.y, rr);  gg = fmaf(s2, h2.z, gg);  bb2 = fmaf(s2, h2.w, bb2);
                rr = fmaf(c2, h3.x, rr);  gg = fmaf(c2, h3.y, gg);  bb2 = fmaf(c2, h3.z, bb2);
                rr = fmaf(s3, h3.w, rr);  gg = fmaf(s3, h4.x, gg);  bb2 = fmaf(s3, h4.y, bb2);
                rr = fmaf(c3, h4.z, rr);  gg = fmaf(c3, h4.w, gg);  bb2 = fmaf(c3, h5.x, bb2);
                rr = fmaf(s4, h5.y, rr);  gg = fmaf(s4, h5.z, gg);  bb2 = fmaf(s4, h5.w, bb2);
                rr = fmaf(c4, h6.x, rr);  gg = fmaf(c4, h6.y, gg);  bb2 = fmaf(c4, h6.z, bb2);
                rr  = __builtin_amdgcn_rcpf(1.0f + __expf(-rr));
                gg  = __builtin_amdgcn_rcpf(1.0f + __expf(-gg));
                bb2 = __builtin_amdgcn_rcpf(1.0f + __expf(-bb2));
                float wt = __expf(-d2) * q.z;
                accR = fmaf(wt, rr,  accR);
                accG = fmaf(wt, gg,  accG);
                accB = fmaf(wt, bb2, accB);
            }
        }
    }

    // ---- reduce partials across 16 waves (ascending chunk == ascending n) ----
    acc[w][lane * 3 + 0] = accR;     // stride-3 write: 2-way bank alias (free)
    acc[w][lane * 3 + 1] = accG;
    acc[w][lane * 3 + 2] = accB;
    __syncthreads();
    if (tid < RPB * 3) {
        float s = 0.0f;
        #pragma unroll
        for (int w2 = 0; w2 < NW; ++w2)
            s += acc[w2][tid];                     // consecutive: conflict-free
        const int idx = blockIdx.x * (RPB * 3) + tid;
        if (idx < 3 * B)
            out[idx] = s;
    }
}

extern "C" void kernel_launch(void* const* d_in, const int* in_sizes, int n_in,
                              void* d_out, int out_size, void* d_ws, size_t ws_size,
                              hipStream_t stream) {
    const float* x       = (const float*)d_in[0];
    const float* rgbsh   = (const float*)d_in[1];
    const float* opacity = (const float*)d_in[2];
    const float* mu      = (const float*)d_in[3];
    const float* scale   = (const float*)d_in[4];
    const float* angle   = (const float*)d_in[5];
    float* out = (float*)d_out;

    const int B = in_sizes[0] / 2;   // 32768
    const int N = in_sizes[2];       // 512

    // workspace: [wsA: N float4][wsB: N float4][wsSh: N*7 float4]
    char* ws = (char*)d_ws;
    float4* wsA  = (float4*)(ws);
    float4* wsB  = (float4*)(ws + (size_t)N * 16);
    float4* wsSh = (float4*)(ws + (size_t)N * 32);

    pre_kernel<<<(N + 255) / 256, 256, 0, stream>>>(rgbsh, opacity, mu, scale,
                                                    angle, wsA, wsB, wsSh, N);
    splat_kernel<<<(B + RPB - 1) / RPB, BDIM, 0, stream>>>(x, wsA, wsB, wsSh,
                                                           out, B);
}